// Round 2
// baseline (10704.906 us; speedup 1.0000x reference)
//
#include <hip/hip_runtime.h>
#include <hip/hip_bf16.h>
#include <cstdint>

typedef __bf16 bf16;
typedef __bf16 bf16x8 __attribute__((ext_vector_type(8)));
typedef float f32x4 __attribute__((ext_vector_type(4)));
typedef unsigned int u32x4 __attribute__((ext_vector_type(4)));

#define B_ 4
#define S_ 2048
#define D_ 2048
#define H_ 16
#define NOPE_ 128
#define ROPE_ 64
#define V_ 128
#define KVR_ 512
#define QK_ 192
#define KD_ 576   // KVR + ROPE

__device__ __forceinline__ bf16 tobf(float f) {
  unsigned u = __float_as_uint(f);
  u += 0x7fffu + ((u >> 16) & 1u);          // RNE
  unsigned short s = (unsigned short)(u >> 16);
  return *reinterpret_cast<bf16*>(&s);
}
__device__ __forceinline__ float tof(bf16 v) {
  unsigned short s = *reinterpret_cast<unsigned short*>(&v);
  return __uint_as_float(((unsigned)s) << 16);
}

// ---------------- elementwise: f32 -> bf16 cast (8 elems/thread) ----------------
__global__ void cast_bf16(const float* __restrict__ in, bf16* __restrict__ out, long n) {
  long i = ((long)blockIdx.x * 256 + threadIdx.x) * 8;
  if (i >= n) return;
  float4 a = *(const float4*)(in + i);
  float4 b = *(const float4*)(in + i + 4);
  bf16x8 v;
  v[0] = tobf(a.x); v[1] = tobf(a.y); v[2] = tobf(a.z); v[3] = tobf(a.w);
  v[4] = tobf(b.x); v[5] = tobf(b.y); v[6] = tobf(b.z); v[7] = tobf(b.w);
  *(bf16x8*)(out + i) = v;
}

// ---------------- wkv_b prep: nope half transposed to (H, KVR, NOPE), v half cast ----------------
__global__ void prep_wkvb(const float* __restrict__ w, bf16* __restrict__ wnT, bf16* __restrict__ wv) {
  int tid = blockIdx.x * 256 + threadIdx.x;      // 16*128*512 = 1048576 threads
  {
    int c = tid & 511, rest = tid >> 9, d = rest & 127, h = rest >> 7;
    wv[tid] = tobf(w[((long)(h * 256 + 128 + d) << 9) + c]);
  }
  {
    int d = tid & 127, rest = tid >> 7, c = rest & 511, h = rest >> 9;
    wnT[tid] = tobf(w[((long)(h * 256 + d) << 9) + c]);
  }
}

// ---------------- generic BT GEMM: C[m][n] = sum_k A[m][k]*Bm[n][k] ----------------
// 128x128 tile, 4 waves (2x2 of 64x64), BK=32, mfma 16x16x32 bf16.
template <typename OutT>
__global__ __launch_bounds__(256)
void gemm_bt(const bf16* __restrict__ A, long lda, long aOffZ,
             const bf16* __restrict__ Bm, long ldb, long bOffZ,
             OutT* __restrict__ C, long ldc, long cOffZ,
             int M, int N, int K)
{
  A += aOffZ * blockIdx.z;
  Bm += bOffZ * blockIdx.z;
  C += cOffZ * blockIdx.z;
  const int m0 = blockIdx.y * 128, n0 = blockIdx.x * 128;
  const int tid = threadIdx.x;
  const int wave = tid >> 6, lane = tid & 63, quad = lane >> 4, r = lane & 15;
  const int wm = (wave >> 1) * 64, wn = (wave & 1) * 64;
  __shared__ __align__(16) bf16 As[128][40];   // +8 pad -> 2-way bank alias (free)
  __shared__ __align__(16) bf16 Bs[128][40];
  f32x4 acc[4][4] = {};
  for (int k0 = 0; k0 < K; k0 += 32) {
    __syncthreads();
#pragma unroll
    for (int it = 0; it < 2; ++it) {
      int idx = tid + it * 256;
      int row = idx >> 2, ch = (idx & 3) * 8;
      long ar = m0 + row; if (ar > (long)M - 1) ar = M - 1;
      *(u32x4*)&As[row][ch] = *(const u32x4*)(A + ar * lda + k0 + ch);
      long br = n0 + row; if (br > (long)N - 1) br = N - 1;
      *(u32x4*)&Bs[row][ch] = *(const u32x4*)(Bm + br * ldb + k0 + ch);
    }
    __syncthreads();
    bf16x8 af[4], bfr[4];
#pragma unroll
    for (int i = 0; i < 4; ++i) af[i] = *(const bf16x8*)&As[wm + i * 16 + r][quad * 8];
#pragma unroll
    for (int j = 0; j < 4; ++j) bfr[j] = *(const bf16x8*)&Bs[wn + j * 16 + r][quad * 8];
#pragma unroll
    for (int i = 0; i < 4; ++i)
#pragma unroll
      for (int j = 0; j < 4; ++j)
        acc[i][j] = __builtin_amdgcn_mfma_f32_16x16x32_bf16(af[i], bfr[j], acc[i][j], 0, 0, 0);
  }
#pragma unroll
  for (int i = 0; i < 4; ++i) {
    int mrow = m0 + wm + i * 16 + quad * 4;
#pragma unroll
    for (int j = 0; j < 4; ++j) {
      int ncol = n0 + wn + j * 16 + r;
      if (ncol < N) {
#pragma unroll
        for (int t = 0; t < 4; ++t) {
          if (mrow + t < M) {
            if constexpr (__is_same(OutT, float))
              C[(long)(mrow + t) * ldc + ncol] = acc[i][j][t];
            else
              C[(long)(mrow + t) * ldc + ncol] = tobf(acc[i][j][t]);
          }
        }
      }
    }
  }
}

// ---------------- kv rmsnorm + rope(k_pe) -> Keff (T,576) bf16, per batch ----------------
__global__ void kv_norm(const float* __restrict__ kvf, const float* __restrict__ w,
                        const float* __restrict__ fcos, const float* __restrict__ fsin,
                        bf16* __restrict__ keff) {
  int row = blockIdx.x * 4 + (threadIdx.x >> 6);     // t in [0,S)
  int lane = threadIdx.x & 63;
  int t = row;
  const float* src = kvf + (long)row * KD_;
  float v[8]; float ss = 0.f;
#pragma unroll
  for (int i = 0; i < 8; ++i) { v[i] = src[lane * 8 + i]; ss += v[i] * v[i]; }
#pragma unroll
  for (int off = 1; off < 64; off <<= 1) ss += __shfl_xor(ss, off, 64);
  float rms = rsqrtf(ss * (1.f / 512.f) + 1e-6f);
  bf16* dst = keff + (long)row * KD_;
#pragma unroll
  for (int i = 0; i < 8; ++i) dst[lane * 8 + i] = tobf(v[i] * rms * w[lane * 8 + i]);
  if (lane < 32) {
    float x1 = src[KVR_ + 2 * lane], x2 = src[KVR_ + 2 * lane + 1];
    float c = fcos[t * 32 + lane], s = fsin[t * 32 + lane];
    dst[KVR_ + 2 * lane]     = tobf(x1 * c - x2 * s);
    dst[KVR_ + 2 * lane + 1] = tobf(x1 * s + x2 * c);
  }
}

// ---------------- kv_c transpose: Keff(T,576)[:, :512] -> kvcT (512,T), per batch ----------------
__global__ void transpose_kvc(const bf16* __restrict__ keff, bf16* __restrict__ kvcT) {
  int c0 = blockIdx.y * 32, t0 = blockIdx.x * 32;
  __shared__ bf16 tile[32][33];
  int x = threadIdx.x & 31, y = threadIdx.x >> 5;   // 32 x 8
#pragma unroll
  for (int k = 0; k < 4; ++k) {
    int t = t0 + y + k * 8;
    tile[y + k * 8][x] = keff[(long)t * KD_ + c0 + x];
  }
  __syncthreads();
#pragma unroll
  for (int k = 0; k < 4; ++k) {
    int c = c0 + y + k * 8;
    kvcT[(long)c * S_ + t0 + x] = tile[x][y + k * 8];
  }
}

// ---------------- q rope: qb(S,H,192)[...,128:192] -> qeff(S,H,576)[...,512:576], per batch ----------------
__global__ void rope_q(const bf16* __restrict__ qb, const float* __restrict__ fcos,
                       const float* __restrict__ fsin, bf16* __restrict__ qeff) {
  long tid = (long)blockIdx.x * 256 + threadIdx.x;  // S*H*32
  int i = tid & 31; int h = (tid >> 5) & 15; long bs = tid >> 9; int t = (int)bs;
  const bf16* src = qb + bs * (H_ * QK_) + h * QK_ + NOPE_ + 2 * i;
  float x1 = tof(src[0]), x2 = tof(src[1]);
  float c = fcos[t * 32 + i], s = fsin[t * 32 + i];
  long o = (bs * H_ + h) * KD_ + KVR_ + 2 * i;
  qeff[o]     = tobf(x1 * c - x2 * s);
  qeff[o + 1] = tobf(x1 * s + x2 * c);
}

// ---------------- flash attention (per batch): one wave per (h, 16-row q tile) ----------------
__global__ __launch_bounds__(64)
void flash_mla(const bf16* __restrict__ Qeff, const bf16* __restrict__ Keff,
               const bf16* __restrict__ kvcT, bf16* __restrict__ Oc)
{
  const int qt = blockIdx.x, h = blockIdx.y;
  const int s0 = qt * 16;
  const int lane = threadIdx.x, quad = lane >> 4, r = lane & 15;
  __shared__ __align__(16) bf16 Ql[16][584];   // 576 + 8 pad
  __shared__ __align__(16) bf16 Pl[16][40];    // 32 + 8 pad

  const bf16* qbase = Qeff + ((long)s0 * H_ + h) * KD_;
  for (int i = lane; i < 16 * 72; i += 64) {
    int row = i / 72, ch = i - row * 72;
    *(u32x4*)&Ql[row][ch * 8] = *(const u32x4*)(qbase + (long)row * (H_ * KD_) + ch * 8);
  }
  __syncthreads();

  f32x4 o[32] = {};
  float mrow[4], lrow[4];
#pragma unroll
  for (int t = 0; t < 4; ++t) { mrow[t] = -INFINITY; lrow[t] = 0.f; }
  const float scale = 0.07216878364870323f;   // 1/sqrt(192)

  const bf16* kb = Keff;
  const bf16* vb = kvcT;
  const int ntiles = (s0 + 16 + 31) >> 5;

  for (int kt = 0; kt < ntiles; ++kt) {
    const int t0 = kt * 32;
    f32x4 sacc[2] = {};
#pragma unroll 2
    for (int kc = 0; kc < 18; ++kc) {
      bf16x8 aq = *(const bf16x8*)&Ql[r][kc * 32 + quad * 8];
#pragma unroll
      for (int ns = 0; ns < 2; ++ns) {
        bf16x8 bk = *(const bf16x8*)(kb + (long)(t0 + ns * 16 + r) * KD_ + kc * 32 + quad * 8);
        sacc[ns] = __builtin_amdgcn_mfma_f32_16x16x32_bf16(aq, bk, sacc[ns], 0, 0, 0);
      }
    }
    float alpha4[4];
#pragma unroll
    for (int tt = 0; tt < 4; ++tt) {
      int srow = s0 + quad * 4 + tt;
#pragma unroll
      for (int ns = 0; ns < 2; ++ns) {
        int tcol = t0 + ns * 16 + r;
        float v = sacc[ns][tt] * scale;
        sacc[ns][tt] = (tcol <= srow) ? v : -INFINITY;
      }
      float mx = fmaxf(sacc[0][tt], sacc[1][tt]);
#pragma unroll
      for (int off = 1; off < 16; off <<= 1) mx = fmaxf(mx, __shfl_xor(mx, off, 64));
      float mnew = fmaxf(mrow[tt], mx);
      float al = __expf(mrow[tt] - mnew);
      float p0 = __expf(sacc[0][tt] - mnew);
      float p1 = __expf(sacc[1][tt] - mnew);
      float rs = p0 + p1;
#pragma unroll
      for (int off = 1; off < 16; off <<= 1) rs += __shfl_xor(rs, off, 64);
      lrow[tt] = lrow[tt] * al + rs;
      mrow[tt] = mnew;
      alpha4[tt] = al;
      Pl[quad * 4 + tt][r]      = tobf(p0);
      Pl[quad * 4 + tt][16 + r] = tobf(p1);
    }
#pragma unroll
    for (int j = 0; j < 32; ++j)
#pragma unroll
      for (int tt = 0; tt < 4; ++tt) o[j][tt] *= alpha4[tt];
    __syncthreads();
    bf16x8 pa = *(const bf16x8*)&Pl[r][quad * 8];
#pragma unroll 4
    for (int j = 0; j < 32; ++j) {
      bf16x8 bv = *(const bf16x8*)(vb + (long)(j * 16 + r) * S_ + t0 + quad * 8);
      o[j] = __builtin_amdgcn_mfma_f32_16x16x32_bf16(pa, bv, o[j], 0, 0, 0);
    }
    __syncthreads();
  }
  // epilogue: normalize + store to Oc (S,H,512)
#pragma unroll
  for (int tt = 0; tt < 4; ++tt) {
    long srow = (long)s0 + quad * 4 + tt;
    bf16* orow = Oc + (srow * H_ + h) * KVR_;
    float li = 1.0f / lrow[tt];
#pragma unroll 8
    for (int j = 0; j < 32; ++j) orow[j * 16 + r] = tobf(o[j][tt] * li);
  }
}

extern "C" void kernel_launch(void* const* d_in, const int* in_sizes, int n_in,
                              void* d_out, int out_size, void* d_ws, size_t ws_size,
                              hipStream_t stream) {
  (void)in_sizes; (void)n_in; (void)out_size; (void)ws_size;
  const float* x     = (const float*)d_in[0];
  const float* wq    = (const float*)d_in[1];
  const float* wkv_a = (const float*)d_in[2];
  const float* kvw   = (const float*)d_in[3];
  const float* wkv_b = (const float*)d_in[4];
  const float* wo    = (const float*)d_in[5];
  const float* fcos  = (const float*)d_in[6];
  const float* fsin  = (const float*)d_in[7];
  float* out = (float*)d_out;

  char* p = (char*)d_ws;
  auto alloc = [&](size_t bytes) { char* q = p; p += (bytes + 255) & ~(size_t)255; return q; };
  const long MR = (long)B_ * S_;                       // 8192 rows total
  // persistent (~94.6 MB)
  bf16* xb   = (bf16*)alloc(MR * D_ * 2);              // 33.55 MB
  bf16* out2 = (bf16*)alloc(MR * D_ * 2);              // 33.55 MB
  bf16* wqb  = (bf16*)alloc((long)H_ * QK_ * D_ * 2);  // 12.58 MB
  bf16* wab  = (bf16*)alloc((long)KD_ * D_ * 2);       // 2.36 MB
  bf16* wob  = (bf16*)alloc((long)D_ * D_ * 2);        // 8.39 MB
  bf16* wbnT = (bf16*)alloc((long)H_ * KVR_ * NOPE_ * 2); // 2.10 MB
  bf16* wbv  = (bf16*)alloc((long)H_ * V_ * KVR_ * 2);    // 2.10 MB
  // per-batch region, reused across b (~93 MB)
  float* kvf = (float*)alloc((long)S_ * KD_ * 4);      // 4.72 MB
  bf16* keff = (bf16*)alloc((long)S_ * KD_ * 2);       // 2.36 MB
  bf16* kvcT = (bf16*)alloc((long)KVR_ * S_ * 2);      // 2.10 MB
  bf16* qb   = (bf16*)alloc((long)S_ * H_ * QK_ * 2);  // 12.58 MB
  bf16* qeff = (bf16*)alloc((long)S_ * H_ * KD_ * 2);  // 37.75 MB
  bf16* oc   = (bf16*)alloc((long)S_ * H_ * KVR_ * 2); // 33.55 MB
  // total ~188 MB

  // 1. casts (once)
  cast_bf16<<<(MR * D_) >> 11, 256, 0, stream>>>(x, xb, MR * D_);
  cast_bf16<<<((long)H_ * QK_ * D_) >> 11, 256, 0, stream>>>(wq, wqb, (long)H_ * QK_ * D_);
  cast_bf16<<<((long)KD_ * D_) >> 11, 256, 0, stream>>>(wkv_a, wab, (long)KD_ * D_);
  cast_bf16<<<((long)D_ * D_) >> 11, 256, 0, stream>>>(wo, wob, (long)D_ * D_);
  prep_wkvb<<<4096, 256, 0, stream>>>(wkv_b, wbnT, wbv);

  for (int b = 0; b < B_; ++b) {
    const bf16* xb_b = xb + (long)b * S_ * D_;
    bf16* out2_b = out2 + (long)b * S_ * D_;
    // 2. kv = x_b @ wkv_a^T  (fp32 out)
    gemm_bt<float><<<dim3(5, 16, 1), 256, 0, stream>>>(xb_b, D_, 0, wab, D_, 0,
                                                       kvf, KD_, 0, S_, KD_, D_);
    // 3. rmsnorm + rope(k_pe) -> keff
    kv_norm<<<S_ / 4, 256, 0, stream>>>(kvf, kvw, fcos, fsin, keff);
    // 4. kv_c transpose
    transpose_kvc<<<dim3(S_ / 32, KVR_ / 32, 1), 256, 0, stream>>>(keff, kvcT);
    // 5. q = x_b @ wq^T (bf16 out)
    gemm_bt<bf16><<<dim3(24, 16, 1), 256, 0, stream>>>(xb_b, D_, 0, wqb, D_, 0,
                                                       qb, H_ * QK_, 0, S_, H_ * QK_, D_);
    // 6. rope q_pe -> qeff[...,512:576]
    rope_q<<<(S_ * H_ * 32) / 256, 256, 0, stream>>>(qb, fcos, fsin, qeff);
    // 7. q_lat per head -> qeff[...,0:512]
    gemm_bt<bf16><<<dim3(4, 16, H_), 256, 0, stream>>>(qb, H_ * QK_, QK_,
                                                       wbnT, NOPE_, (long)KVR_ * NOPE_,
                                                       qeff, H_ * KD_, KD_, S_, KVR_, NOPE_);
    // 8. flash attention -> oc
    flash_mla<<<dim3(S_ / 16, H_, 1), 64, 0, stream>>>(qeff, keff, kvcT, oc);
    // 9. per-head V projection -> out2_b
    gemm_bt<bf16><<<dim3(1, 16, H_), 256, 0, stream>>>(oc, H_ * KVR_, KVR_,
                                                       wbv, KVR_, (long)V_ * KVR_,
                                                       out2_b, D_, V_, S_, V_, KVR_);
  }
  // 10. final: out = out2 @ wo^T (fp32 out, all batches at once)
  gemm_bt<float><<<dim3(16, 64, 1), 256, 0, stream>>>(out2, D_, 0, wob, D_, 0,
                                                      out, D_, 0, MR, D_, D_);
}

// Round 3
// 2579.032 us; speedup vs baseline: 4.1507x; 4.1507x over previous
//
#include <hip/hip_runtime.h>
#include <hip/hip_bf16.h>
#include <cstdint>

typedef __bf16 bf16;
typedef __bf16 bf16x8 __attribute__((ext_vector_type(8)));
typedef float f32x4 __attribute__((ext_vector_type(4)));
typedef unsigned int u32x4 __attribute__((ext_vector_type(4)));

#define B_ 4
#define S_ 2048
#define D_ 2048
#define H_ 16
#define NOPE_ 128
#define ROPE_ 64
#define V_ 128
#define KVR_ 512
#define QK_ 192
#define KD_ 576   // KVR + ROPE

__device__ __forceinline__ bf16 tobf(float f) {
  unsigned u = __float_as_uint(f);
  u += 0x7fffu + ((u >> 16) & 1u);          // RNE
  unsigned short s = (unsigned short)(u >> 16);
  return *reinterpret_cast<bf16*>(&s);
}
__device__ __forceinline__ float tof(bf16 v) {
  unsigned short s = *reinterpret_cast<unsigned short*>(&v);
  return __uint_as_float(((unsigned)s) << 16);
}

// ---------------- elementwise: f32 -> bf16 cast (8 elems/thread) ----------------
__global__ void cast_bf16(const float* __restrict__ in, bf16* __restrict__ out, long n) {
  long i = ((long)blockIdx.x * 256 + threadIdx.x) * 8;
  if (i >= n) return;
  float4 a = *(const float4*)(in + i);
  float4 b = *(const float4*)(in + i + 4);
  bf16x8 v;
  v[0] = tobf(a.x); v[1] = tobf(a.y); v[2] = tobf(a.z); v[3] = tobf(a.w);
  v[4] = tobf(b.x); v[5] = tobf(b.y); v[6] = tobf(b.z); v[7] = tobf(b.w);
  *(bf16x8*)(out + i) = v;
}

// ---------------- wkv_b prep: nope half transposed to (H, KVR, NOPE), v half cast ----------------
__global__ void prep_wkvb(const float* __restrict__ w, bf16* __restrict__ wnT, bf16* __restrict__ wv) {
  int tid = blockIdx.x * 256 + threadIdx.x;      // 16*128*512 = 1048576 threads
  {
    int c = tid & 511, rest = tid >> 9, d = rest & 127, h = rest >> 7;
    wv[tid] = tobf(w[((long)(h * 256 + 128 + d) << 9) + c]);
  }
  {
    int d = tid & 127, rest = tid >> 7, c = rest & 511, h = rest >> 9;
    wnT[tid] = tobf(w[((long)(h * 256 + d) << 9) + c]);
  }
}

// ---------------- generic BT GEMM: C[m][n] = sum_k A[m][k]*Bm[n][k] ----------------
template <typename OutT>
__global__ __launch_bounds__(256)
void gemm_bt(const bf16* __restrict__ A, long lda, long aOffZ,
             const bf16* __restrict__ Bm, long ldb, long bOffZ,
             OutT* __restrict__ C, long ldc, long cOffZ,
             int M, int N, int K)
{
  A += aOffZ * blockIdx.z;
  Bm += bOffZ * blockIdx.z;
  C += cOffZ * blockIdx.z;
  const int m0 = blockIdx.y * 128, n0 = blockIdx.x * 128;
  const int tid = threadIdx.x;
  const int wave = tid >> 6, lane = tid & 63, quad = lane >> 4, r = lane & 15;
  const int wm = (wave >> 1) * 64, wn = (wave & 1) * 64;
  __shared__ __align__(16) bf16 As[128][40];
  __shared__ __align__(16) bf16 Bs[128][40];
  f32x4 acc[4][4] = {};
  for (int k0 = 0; k0 < K; k0 += 32) {
    __syncthreads();
#pragma unroll
    for (int it = 0; it < 2; ++it) {
      int idx = tid + it * 256;
      int row = idx >> 2, ch = (idx & 3) * 8;
      long ar = m0 + row; if (ar > (long)M - 1) ar = M - 1;
      *(u32x4*)&As[row][ch] = *(const u32x4*)(A + ar * lda + k0 + ch);
      long br = n0 + row; if (br > (long)N - 1) br = N - 1;
      *(u32x4*)&Bs[row][ch] = *(const u32x4*)(Bm + br * ldb + k0 + ch);
    }
    __syncthreads();
    bf16x8 af[4], bfr[4];
#pragma unroll
    for (int i = 0; i < 4; ++i) af[i] = *(const bf16x8*)&As[wm + i * 16 + r][quad * 8];
#pragma unroll
    for (int j = 0; j < 4; ++j) bfr[j] = *(const bf16x8*)&Bs[wn + j * 16 + r][quad * 8];
#pragma unroll
    for (int i = 0; i < 4; ++i)
#pragma unroll
      for (int j = 0; j < 4; ++j)
        acc[i][j] = __builtin_amdgcn_mfma_f32_16x16x32_bf16(af[i], bfr[j], acc[i][j], 0, 0, 0);
  }
#pragma unroll
  for (int i = 0; i < 4; ++i) {
    int mrow = m0 + wm + i * 16 + quad * 4;
#pragma unroll
    for (int j = 0; j < 4; ++j) {
      int ncol = n0 + wn + j * 16 + r;
      if (ncol < N) {
#pragma unroll
        for (int t = 0; t < 4; ++t) {
          if (mrow + t < M) {
            if constexpr (__is_same(OutT, float))
              C[(long)(mrow + t) * ldc + ncol] = acc[i][j][t];
            else
              C[(long)(mrow + t) * ldc + ncol] = tobf(acc[i][j][t]);
          }
        }
      }
    }
  }
}

// ---------------- kv rmsnorm + rope(k_pe) -> Keff (T,576) bf16, per batch ----------------
__global__ void kv_norm(const float* __restrict__ kvf, const float* __restrict__ w,
                        const float* __restrict__ fcos, const float* __restrict__ fsin,
                        bf16* __restrict__ keff) {
  int row = blockIdx.x * 4 + (threadIdx.x >> 6);     // t in [0,S)
  int lane = threadIdx.x & 63;
  int t = row;
  const float* src = kvf + (long)row * KD_;
  float v[8]; float ss = 0.f;
#pragma unroll
  for (int i = 0; i < 8; ++i) { v[i] = src[lane * 8 + i]; ss += v[i] * v[i]; }
#pragma unroll
  for (int off = 1; off < 64; off <<= 1) ss += __shfl_xor(ss, off, 64);
  float rms = rsqrtf(ss * (1.f / 512.f) + 1e-6f);
  bf16* dst = keff + (long)row * KD_;
#pragma unroll
  for (int i = 0; i < 8; ++i) dst[lane * 8 + i] = tobf(v[i] * rms * w[lane * 8 + i]);
  if (lane < 32) {
    float x1 = src[KVR_ + 2 * lane], x2 = src[KVR_ + 2 * lane + 1];
    float c = fcos[t * 32 + lane], s = fsin[t * 32 + lane];
    dst[KVR_ + 2 * lane]     = tobf(x1 * c - x2 * s);
    dst[KVR_ + 2 * lane + 1] = tobf(x1 * s + x2 * c);
  }
}

// ---------------- kv_c transpose: Keff(T,576)[:, :512] -> kvcT (512,T), per batch ----------------
__global__ void transpose_kvc(const bf16* __restrict__ keff, bf16* __restrict__ kvcT) {
  int c0 = blockIdx.y * 32, t0 = blockIdx.x * 32;
  __shared__ bf16 tile[32][33];
  int x = threadIdx.x & 31, y = threadIdx.x >> 5;   // 32 x 8
#pragma unroll
  for (int k = 0; k < 4; ++k) {
    int t = t0 + y + k * 8;
    tile[y + k * 8][x] = keff[(long)t * KD_ + c0 + x];
  }
  __syncthreads();
#pragma unroll
  for (int k = 0; k < 4; ++k) {
    int c = c0 + y + k * 8;
    kvcT[(long)c * S_ + t0 + x] = tile[x][y + k * 8];
  }
}

// ---------------- q rope: qb(S,H,192)[...,128:192] -> qeff(S,H,576)[...,512:576], per batch ----------------
__global__ void rope_q(const bf16* __restrict__ qb, const float* __restrict__ fcos,
                       const float* __restrict__ fsin, bf16* __restrict__ qeff) {
  long tid = (long)blockIdx.x * 256 + threadIdx.x;  // S*H*32
  int i = tid & 31; int h = (tid >> 5) & 15; long bs = tid >> 9; int t = (int)bs;
  const bf16* src = qb + bs * (H_ * QK_) + h * QK_ + NOPE_ + 2 * i;
  float x1 = tof(src[0]), x2 = tof(src[1]);
  float c = fcos[t * 32 + i], s = fsin[t * 32 + i];
  long o = (bs * H_ + h) * KD_ + KVR_ + 2 * i;
  qeff[o]     = tobf(x1 * c - x2 * s);
  qeff[o + 1] = tobf(x1 * s + x2 * c);
}

// ---------------- flash attention v2 (per batch) ----------------
// Block = 4 waves. blockIdx.x = pair(0..31) + 32*h. Two phases: q-tile qt=pair, then qt=63-pair
// (32-row q tiles; total K-tile work = 65 per block, uniform). Within a phase:
// wave (rowHalf=w&1, colHalf=w>>1) owns rows [s0+16*rowHalf, +16) x V-cols [256*colHalf, +256).
// Q fragments in registers (18 x bf16x8). K tile 32x576 and V tile 512x32 staged in LDS.
// QK^T duplicated across colHalf pairs (cheaper than 128-VGPR accumulators + spill risk).
__global__ __launch_bounds__(256, 2)
void flash_mla(const bf16* __restrict__ Qeff, const bf16* __restrict__ Keff,
               const bf16* __restrict__ kvcT, bf16* __restrict__ Oc)
{
  const int pair = blockIdx.x & 31, h = blockIdx.x >> 5;
  const int tid = threadIdx.x;
  const int wave = tid >> 6, lane = tid & 63, quad = lane >> 4, r = lane & 15;
  const int rowHalf = wave & 1, colHalf = wave >> 1;
  const int cbase = colHalf * 256;

  __shared__ __align__(16) bf16 Ks[32][584];     // 37,376 B  (stride 584: 2-way free)
  __shared__ __align__(16) bf16 Vs[512][36];     // 36,864 B  (stride 36: <=2-way)
  __shared__ __align__(16) bf16 Pl[2][16][40];   //  2,560 B
  const float scale = 0.07216878364870323f;      // 1/sqrt(192)

#pragma unroll 1
  for (int phase = 0; phase < 2; ++phase) {
    const int qt = phase ? (63 - pair) : pair;
    const int s0 = qt * 32;
    const int r0 = s0 + rowHalf * 16;
    const int nt = qt + 1;                       // K tiles needed (keys <= s0+32)

    // Q fragments: rows r0..r0+15, all 576 k
    bf16x8 aq[18];
    const bf16* qrow = Qeff + ((long)(r0 + r) * H_ + h) * KD_;
#pragma unroll
    for (int kc = 0; kc < 18; ++kc) aq[kc] = *(const bf16x8*)(qrow + kc * 32 + quad * 8);

    f32x4 o[16] = {};                            // 16 rows x 256 cols accumulator
    float mrow[4], lrow[4];
#pragma unroll
    for (int t = 0; t < 4; ++t) { mrow[t] = -INFINITY; lrow[t] = 0.f; }

    for (int kt = 0; kt < nt; ++kt) {
      const int t0 = kt * 32;
      __syncthreads();                           // LDS safe to overwrite
      // stage K tile: 32x576 elems = 2304 16B-chunks, 9/thread
#pragma unroll
      for (int i = 0; i < 9; ++i) {
        int c = tid + i * 256;
        int row = c / 72, col = c - row * 72;
        *(u32x4*)&Ks[row][col * 8] = *(const u32x4*)(Keff + (long)(t0 + row) * KD_ + col * 8);
      }
      // stage V tile: 512x32 elems = 2048 16B-chunks, 8/thread
#pragma unroll
      for (int i = 0; i < 8; ++i) {
        int c = tid + i * 256;
        int row = c >> 2, col = c & 3;
        *(u32x4*)&Vs[row][col * 8] = *(const u32x4*)(kvcT + (long)row * S_ + t0 + col * 8);
      }
      __syncthreads();
      // QK^T: 16 rows x 32 keys
      f32x4 sacc[2] = {};
#pragma unroll
      for (int kc = 0; kc < 18; ++kc) {
        bf16x8 b0 = *(const bf16x8*)&Ks[r][kc * 32 + quad * 8];
        bf16x8 b1 = *(const bf16x8*)&Ks[16 + r][kc * 32 + quad * 8];
        sacc[0] = __builtin_amdgcn_mfma_f32_16x16x32_bf16(aq[kc], b0, sacc[0], 0, 0, 0);
        sacc[1] = __builtin_amdgcn_mfma_f32_16x16x32_bf16(aq[kc], b1, sacc[1], 0, 0, 0);
      }
      // online softmax (rows = quad*4+tt, cols = t0 + ns*16 + r)
      float alpha4[4];
#pragma unroll
      for (int tt = 0; tt < 4; ++tt) {
        int srow = r0 + quad * 4 + tt;
        float s0v = sacc[0][tt] * scale;
        float s1v = sacc[1][tt] * scale;
        s0v = (t0 + r <= srow) ? s0v : -INFINITY;
        s1v = (t0 + 16 + r <= srow) ? s1v : -INFINITY;
        float mx = fmaxf(s0v, s1v);
#pragma unroll
        for (int off = 1; off < 16; off <<= 1) mx = fmaxf(mx, __shfl_xor(mx, off, 64));
        float mnew = fmaxf(mrow[tt], mx);
        float al = __expf(mrow[tt] - mnew);
        float p0 = __expf(s0v - mnew);
        float p1 = __expf(s1v - mnew);
        float rs = p0 + p1;
#pragma unroll
        for (int off = 1; off < 16; off <<= 1) rs += __shfl_xor(rs, off, 64);
        lrow[tt] = lrow[tt] * al + rs;
        mrow[tt] = mnew;
        alpha4[tt] = al;
        if (wave < 2) {                          // waves 2,3 computed identical values
          Pl[rowHalf][quad * 4 + tt][r]      = tobf(p0);
          Pl[rowHalf][quad * 4 + tt][16 + r] = tobf(p1);
        }
      }
      // rescale o — FULLY unrolled (runtime indexing would demote o to scratch)
#pragma unroll
      for (int j = 0; j < 16; ++j) {
#pragma unroll
        for (int tt = 0; tt < 4; ++tt) o[j][tt] *= alpha4[tt];
      }
      __syncthreads();                           // P visible
      // PV: o[16 rows x 256 cols] += P(16x32) @ V(32x256)
      bf16x8 pa = *(const bf16x8*)&Pl[rowHalf][r][quad * 8];
#pragma unroll
      for (int j = 0; j < 16; ++j) {
        bf16x8 bv = *(const bf16x8*)&Vs[cbase + j * 16 + r][quad * 8];
        o[j] = __builtin_amdgcn_mfma_f32_16x16x32_bf16(pa, bv, o[j], 0, 0, 0);
      }
    }
    // epilogue: normalize, store Oc (S,H,512)
#pragma unroll
    for (int tt = 0; tt < 4; ++tt) {
      long srow = (long)(r0 + quad * 4 + tt);
      bf16* orow = Oc + (srow * H_ + h) * KVR_ + cbase;
      float li = 1.0f / lrow[tt];
#pragma unroll
      for (int j = 0; j < 16; ++j) orow[j * 16 + r] = tobf(o[j][tt] * li);
    }
  }
}

extern "C" void kernel_launch(void* const* d_in, const int* in_sizes, int n_in,
                              void* d_out, int out_size, void* d_ws, size_t ws_size,
                              hipStream_t stream) {
  (void)in_sizes; (void)n_in; (void)out_size; (void)ws_size;
  const float* x     = (const float*)d_in[0];
  const float* wq    = (const float*)d_in[1];
  const float* wkv_a = (const float*)d_in[2];
  const float* kvw   = (const float*)d_in[3];
  const float* wkv_b = (const float*)d_in[4];
  const float* wo    = (const float*)d_in[5];
  const float* fcos  = (const float*)d_in[6];
  const float* fsin  = (const float*)d_in[7];
  float* out = (float*)d_out;

  char* p = (char*)d_ws;
  auto alloc = [&](size_t bytes) { char* q = p; p += (bytes + 255) & ~(size_t)255; return q; };
  const long MR = (long)B_ * S_;                       // 8192 rows total
  // persistent (~94.6 MB)
  bf16* xb   = (bf16*)alloc(MR * D_ * 2);
  bf16* out2 = (bf16*)alloc(MR * D_ * 2);
  bf16* wqb  = (bf16*)alloc((long)H_ * QK_ * D_ * 2);
  bf16* wab  = (bf16*)alloc((long)KD_ * D_ * 2);
  bf16* wob  = (bf16*)alloc((long)D_ * D_ * 2);
  bf16* wbnT = (bf16*)alloc((long)H_ * KVR_ * NOPE_ * 2);
  bf16* wbv  = (bf16*)alloc((long)H_ * V_ * KVR_ * 2);
  // per-batch region, reused across b (~93 MB)
  float* kvf = (float*)alloc((long)S_ * KD_ * 4);
  bf16* keff = (bf16*)alloc((long)S_ * KD_ * 2);
  bf16* kvcT = (bf16*)alloc((long)KVR_ * S_ * 2);
  bf16* qb   = (bf16*)alloc((long)S_ * H_ * QK_ * 2);
  bf16* qeff = (bf16*)alloc((long)S_ * H_ * KD_ * 2);
  bf16* oc   = (bf16*)alloc((long)S_ * H_ * KVR_ * 2);

  // 1. casts (once)
  cast_bf16<<<(MR * D_) >> 11, 256, 0, stream>>>(x, xb, MR * D_);
  cast_bf16<<<((long)H_ * QK_ * D_) >> 11, 256, 0, stream>>>(wq, wqb, (long)H_ * QK_ * D_);
  cast_bf16<<<((long)KD_ * D_) >> 11, 256, 0, stream>>>(wkv_a, wab, (long)KD_ * D_);
  cast_bf16<<<((long)D_ * D_) >> 11, 256, 0, stream>>>(wo, wob, (long)D_ * D_);
  prep_wkvb<<<4096, 256, 0, stream>>>(wkv_b, wbnT, wbv);

  for (int b = 0; b < B_; ++b) {
    const bf16* xb_b = xb + (long)b * S_ * D_;
    bf16* out2_b = out2 + (long)b * S_ * D_;
    gemm_bt<float><<<dim3(5, 16, 1), 256, 0, stream>>>(xb_b, D_, 0, wab, D_, 0,
                                                       kvf, KD_, 0, S_, KD_, D_);
    kv_norm<<<S_ / 4, 256, 0, stream>>>(kvf, kvw, fcos, fsin, keff);
    transpose_kvc<<<dim3(S_ / 32, KVR_ / 32, 1), 256, 0, stream>>>(keff, kvcT);
    gemm_bt<bf16><<<dim3(24, 16, 1), 256, 0, stream>>>(xb_b, D_, 0, wqb, D_, 0,
                                                       qb, H_ * QK_, 0, S_, H_ * QK_, D_);
    rope_q<<<(S_ * H_ * 32) / 256, 256, 0, stream>>>(qb, fcos, fsin, qeff);
    gemm_bt<bf16><<<dim3(4, 16, H_), 256, 0, stream>>>(qb, H_ * QK_, QK_,
                                                       wbnT, NOPE_, (long)KVR_ * NOPE_,
                                                       qeff, H_ * KD_, KD_, S_, KVR_, NOPE_);
    flash_mla<<<dim3(512), 256, 0, stream>>>(qeff, keff, kvcT, oc);
    gemm_bt<bf16><<<dim3(1, 16, H_), 256, 0, stream>>>(oc, H_ * KVR_, KVR_,
                                                       wbv, KVR_, (long)V_ * KVR_,
                                                       out2_b, D_, V_, S_, V_, KVR_);
  }
  gemm_bt<float><<<dim3(16, 64, 1), 256, 0, stream>>>(out2, D_, 0, wob, D_, 0,
                                                      out, D_, 0, MR, D_, D_);
}